// Round 10
// baseline (327.116 us; speedup 1.0000x reference)
//
#include <hip/hip_runtime.h>
#include <cstdint>
#include <cstddef>

#define PASSA_EDGES 8192
#define PASSB_CAP   12288   // LDS csr-image capacity (ints); max bucket ~8700 for this input

// ---------------- bf16 helpers ----------------

__device__ __forceinline__ unsigned short f2bf(float f) {  // RNE
    unsigned int u = __float_as_uint(f);
    u += 0x7FFFu + ((u >> 16) & 1u);
    return (unsigned short)(u >> 16);
}

// fma 8 bf16 (packed in uint4) * w into acc[8]
__device__ __forceinline__ void bf8_fma(uint4 u, float w, float* acc) {
    acc[0] += __uint_as_float(u.x << 16) * w;
    acc[1] += __uint_as_float(u.x & 0xFFFF0000u) * w;
    acc[2] += __uint_as_float(u.y << 16) * w;
    acc[3] += __uint_as_float(u.y & 0xFFFF0000u) * w;
    acc[4] += __uint_as_float(u.z << 16) * w;
    acc[5] += __uint_as_float(u.z & 0xFFFF0000u) * w;
    acc[6] += __uint_as_float(u.w << 16) * w;
    acc[7] += __uint_as_float(u.w & 0xFFFF0000u) * w;
}
__device__ __forceinline__ void bf8_unpack(uint4 u, float* v) {
    v[0] = __uint_as_float(u.x << 16);
    v[1] = __uint_as_float(u.x & 0xFFFF0000u);
    v[2] = __uint_as_float(u.y << 16);
    v[3] = __uint_as_float(u.y & 0xFFFF0000u);
    v[4] = __uint_as_float(u.z << 16);
    v[5] = __uint_as_float(u.z & 0xFFFF0000u);
    v[6] = __uint_as_float(u.w << 16);
    v[7] = __uint_as_float(u.w & 0xFFFF0000u);
}

// ---------------- bucket cursor init ----------------

__global__ void bcur_init(int* __restrict__ bcur, int NBUCK, int CAP) {
    int b = threadIdx.x;
    if (b < NBUCK) bcur[b] = b * CAP;
}

// ---------------- pass A: bin (src,dst) by coarse dst bucket into slabs ----------------

__global__ __launch_bounds__(256) void passA(const int* __restrict__ src,
                                             const int* __restrict__ dst,
                                             int* __restrict__ bcur,
                                             int2* __restrict__ bbuf, int E,
                                             int CAP, int shift) {
    __shared__ int2 bins[PASSA_EDGES];
    __shared__ int  cnt[256], off[256], cur[256], gbase[256];
    const int t  = threadIdx.x;
    const int e0 = blockIdx.x * PASSA_EDGES;
    const int n  = min(PASSA_EDGES, E - e0);

    cnt[t] = 0;
    __syncthreads();
    for (int i = t; i < n; i += 256) atomicAdd(&cnt[dst[e0 + i] >> shift], 1);
    __syncthreads();

    int v = cnt[t];
    off[t] = v;
    __syncthreads();
    for (int o = 1; o < 256; o <<= 1) {
        int u = (t >= o) ? off[t - o] : 0;
        __syncthreads();
        off[t] += u;
        __syncthreads();
    }
    int excl = off[t] - v;
    off[t]   = excl;
    cur[t]   = excl;
    __syncthreads();

    for (int i = t; i < n; i += 256) {
        int d = dst[e0 + i];
        int s = src[e0 + i];
        int p = atomicAdd(&cur[d >> shift], 1);
        bins[p] = make_int2(s, d);
    }
    if (cnt[t] > 0) gbase[t] = atomicAdd(&bcur[t], cnt[t]);
    __syncthreads();

    const int w = t >> 6, lane = t & 63;
    for (int b = w; b < 256; b += 4) {
        int c = cnt[b];
        if (c == 0) continue;
        int lo  = off[b], go = gbase[b];
        int lim = (b + 1) * CAP;
        if (go + c > lim) c = max(0, lim - go);
        for (int i = lane; i < c; i += 64) bbuf[go + i] = bins[lo + i];
    }
}

// ---------------- per-bucket histogram + dis ----------------

__global__ __launch_bounds__(256) void hist_dis(const int2* __restrict__ bbuf,
                                                const int* __restrict__ bcur,
                                                int* __restrict__ hist,
                                                float* __restrict__ dis,
                                                int N, int CAP, int shift) {
    __shared__ int cnt[1024];
    const int b     = blockIdx.x;
    const int node0 = b << shift;
    const int nn    = min(1 << shift, N - node0);
    for (int j = threadIdx.x; j < nn; j += 256) cnt[j] = 0;
    __syncthreads();
    const int start = b * CAP, end = bcur[b];
    for (int e = start + threadIdx.x; e < end; e += 256)
        atomicAdd(&cnt[bbuf[e].y - node0], 1);
    __syncthreads();
    for (int j = threadIdx.x; j < nn; j += 256) {
        int c = cnt[j];
        hist[node0 + j] = c;
        dis[node0 + j]  = rsqrtf((float)(c + 1));  // +1 self loop
    }
}

// ---------------- 3-phase exclusive scan hist[0..N) -> ptr[0..N] ----------------

__global__ __launch_bounds__(256) void scan_partial(const int* __restrict__ hist,
                                                    int* __restrict__ partials, int N) {
    __shared__ int red[256];
    const int t    = threadIdx.x;
    const int base = blockIdx.x * 1024 + t * 4;
    int s = 0;
    if (base + 3 < N) {
        int4 v = *(const int4*)&hist[base];
        s = v.x + v.y + v.z + v.w;
    } else {
        for (int i = 0; i < 4; i++)
            if (base + i < N) s += hist[base + i];
    }
    red[t] = s;
    __syncthreads();
    for (int off = 128; off; off >>= 1) {
        if (t < off) red[t] += red[t + off];
        __syncthreads();
    }
    if (t == 0) partials[blockIdx.x] = red[0];
}

__global__ __launch_bounds__(256) void scan_offsets(int* __restrict__ partials, int NB) {
    __shared__ int tmp[256];
    const int t = threadIdx.x;
    int v = (t < NB) ? partials[t] : 0;
    tmp[t] = v;
    __syncthreads();
    for (int off = 1; off < 256; off <<= 1) {
        int u = (t >= off) ? tmp[t - off] : 0;
        __syncthreads();
        tmp[t] += u;
        __syncthreads();
    }
    if (t < NB) partials[t] = tmp[t] - v;
}

__global__ __launch_bounds__(256) void scan_apply(const int* __restrict__ hist,
                                                  const int* __restrict__ partials,
                                                  int* __restrict__ ptr, int N) {
    __shared__ int tsum[256];
    const int t    = threadIdx.x;
    const int base = blockIdx.x * 1024 + t * 4;
    int v[4];
    int s = 0;
    for (int i = 0; i < 4; i++) {
        v[i] = (base + i < N) ? hist[base + i] : 0;
        s += v[i];
    }
    tsum[t] = s;
    __syncthreads();
    for (int off = 1; off < 256; off <<= 1) {
        int u = (t >= off) ? tsum[t - off] : 0;
        __syncthreads();
        tsum[t] += u;
        __syncthreads();
    }
    int run = partials[blockIdx.x] + tsum[t] - s;
    for (int i = 0; i < 4; i++) {
        if (base + i < N) {
            ptr[base + i] = run;
            run += v[i];
        }
    }
    if (base <= N - 1 && N - 1 < base + 4) ptr[N] = run;  // total = E
}

// ---------------- pass B: per-bucket LDS scatter -> contiguous csr write ----------------

__global__ __launch_bounds__(256) void passB(const int2* __restrict__ bbuf,
                                             const int* __restrict__ bcur,
                                             const int* __restrict__ ptr,
                                             int* __restrict__ csr,
                                             int N, int CAP, int shift) {
    __shared__ int lcnt[1024];
    __shared__ int lcsr[PASSB_CAP];
    const int b     = blockIdx.x;
    const int node0 = b << shift;
    const int nn    = min(1 << shift, N - node0);
    const int cbase = ptr[node0];
    const int csize = ptr[node0 + nn] - cbase;

    for (int j = threadIdx.x; j < nn; j += 256) lcnt[j] = ptr[node0 + j] - cbase;
    __syncthreads();

    const int start = b * CAP, end = bcur[b];
    if (csize <= PASSB_CAP) {
        for (int e = start + threadIdx.x; e < end; e += 256) {
            int2 pr = bbuf[e];
            int  p  = atomicAdd(&lcnt[pr.y - node0], 1);
            lcsr[p] = pr.x;
        }
        __syncthreads();
        for (int i = threadIdx.x; i < csize; i += 256) csr[cbase + i] = lcsr[i];
    } else {  // fallback: direct global scatter
        for (int e = start + threadIdx.x; e < end; e += 256) {
            int2 pr = bbuf[e];
            int  p  = atomicAdd(&lcnt[pr.y - node0], 1);
            csr[cbase + p] = pr.x;
        }
    }
}

// ---------------- GEMM: Yb[N x 64](bf16) = X[N x K] @ W[K x 64] ----------------
// #pragma unroll 2 REQUIRED (full unroll -> 256 VGPR + scratch spill, R6).

template <int K>
__global__ __launch_bounds__(256) void gemm64_bf16(const float* __restrict__ X,
                                                   const float* __restrict__ W,
                                                   unsigned short* __restrict__ Yb, int N) {
    constexpr int LDX = K + 4;
    __shared__ float xs[64 * LDX];
    __shared__ float ws[K * 64];
    const int tid  = threadIdx.x;
    const int row0 = blockIdx.x * 64;

    const float4* W4 = (const float4*)W;
    for (int i = tid; i < K * 16; i += 256) ((float4*)ws)[i] = W4[i];

    const float4* X4  = (const float4*)(X + (size_t)row0 * K);
    const int     nf4 = (row0 < N ? min(64, N - row0) : 0) * (K / 4);
    for (int i = tid; i < 16 * K; i += 256) {
        float4 v = make_float4(0.f, 0.f, 0.f, 0.f);
        if (i < nf4) v = X4[i];
        int r  = i / (K / 4);
        int kk = (i % (K / 4)) * 4;
        *(float4*)&xs[r * LDX + kk] = v;
    }
    __syncthreads();

    const int cg = tid & 15;
    const int rg = tid >> 4;

    float acc[4][4] = {};
#pragma unroll 2
    for (int k = 0; k < K; k += 4) {
        float4 xf[4], wf[4];
#pragma unroll
        for (int i = 0; i < 4; i++) xf[i] = *(const float4*)&xs[(rg * 4 + i) * LDX + k];
#pragma unroll
        for (int j = 0; j < 4; j++) wf[j] = *(const float4*)&ws[(k + j) * 64 + cg * 4];
#pragma unroll
        for (int i = 0; i < 4; i++) {
            float4 xv = xf[i];
            acc[i][0] += xv.x * wf[0].x + xv.y * wf[1].x + xv.z * wf[2].x + xv.w * wf[3].x;
            acc[i][1] += xv.x * wf[0].y + xv.y * wf[1].y + xv.z * wf[2].y + xv.w * wf[3].y;
            acc[i][2] += xv.x * wf[0].z + xv.y * wf[1].z + xv.z * wf[2].z + xv.w * wf[3].z;
            acc[i][3] += xv.x * wf[0].w + xv.y * wf[1].w + xv.z * wf[2].w + xv.w * wf[3].w;
        }
    }

#pragma unroll
    for (int i = 0; i < 4; i++) {
        int r = row0 + rg * 4 + i;
        if (r < N) {
            ushort4 o;
            o.x = f2bf(acc[i][0]); o.y = f2bf(acc[i][1]);
            o.z = f2bf(acc[i][2]); o.w = f2bf(acc[i][3]);
            *(ushort4*)&Yb[(size_t)r * 64 + cg * 4] = o;
        }
    }
}

// ---------------- gather core: acc[8] += sum_e B[src_e]*dis[src_e] ----------------
// lane = eg*8+co: eg in [0,8) edge slot, co in [0,8) channel octet (16 B load).
// 8 edges per group, 2 groups (independent loads) per iteration for MLP.
// Overrun groups read row 0 with w=0 (staged regs are 0) -- harmless.

__device__ __forceinline__ void gather8(const unsigned short* __restrict__ B,
                                        const int* __restrict__ csr,
                                        const float* __restrict__ dis,
                                        int s0, int s1, int lane, int eg, int co,
                                        float* acc) {
    for (int base = s0; base < s1; base += 64) {
        int   sv = 0;
        float wv = 0.0f;
        int   e  = base + lane;
        if (e < s1) {
            sv = csr[e];
            wv = dis[sv];
        }
        const int cnt = min(64, s1 - base);
        for (int gg = 0; gg < cnt; gg += 16) {
            int   sA = __shfl(sv, gg + eg);
            float wA = __shfl(wv, gg + eg);
            int   sB = __shfl(sv, gg + 8 + eg);
            float wB = __shfl(wv, gg + 8 + eg);
            uint4 uA = *(const uint4*)&B[(size_t)sA * 64 + co * 8];
            uint4 uB = *(const uint4*)&B[(size_t)sB * 64 + co * 8];
            bf8_fma(uA, wA, acc);
            bf8_fma(uB, wB, acc);
        }
    }
#pragma unroll
    for (int off = 8; off <= 32; off <<= 1)
#pragma unroll
        for (int i = 0; i < 8; i++) acc[i] += __shfl_xor(acc[i], off);
}

// ---------------- layer 1: pull-agg + relu + fused gemm2 -> bf16 hw ----------------

__global__ __launch_bounds__(256) void agg_l1(const unsigned short* __restrict__ B,
                                              const int* __restrict__ csr,
                                              const int* __restrict__ ptr,
                                              const float* __restrict__ dis,
                                              const float* __restrict__ b1,
                                              const float* __restrict__ W2,
                                              unsigned short* __restrict__ hw, int N) {
    __shared__ float w2s[64 * 64];
    for (int i = threadIdx.x; i < 1024; i += 256)
        ((float4*)w2s)[i] = ((const float4*)W2)[i];
    __syncthreads();

    const int wid  = threadIdx.x >> 6;
    const int lane = threadIdx.x & 63;
    const int eg   = lane >> 3;
    const int co   = lane & 7;

    for (int g = 0; g < 4; g++) {
        const int row = blockIdx.x * 16 + g * 4 + wid;
        if (row >= N) continue;

        const int   s0 = ptr[row];
        const int   s1 = ptr[row + 1];
        const float di = dis[row];

        float acc[8] = {};
        gather8(B, csr, dis, s0, s1, lane, eg, co, acc);

        uint4 us = *(const uint4*)&B[(size_t)row * 64 + co * 8];
        float bs[8];
        bf8_unpack(us, bs);
        float bb[8];
        *(float4*)&bb[0] = *(const float4*)&b1[co * 8];
        *(float4*)&bb[4] = *(const float4*)&b1[co * 8 + 4];

        float h[8];
#pragma unroll
        for (int i = 0; i < 8; i++)
            h[i] = fmaxf((acc[i] + bs[i] * di) * di + bb[i], 0.f);

        // fused gemm2: dest lane (eg,co) covers out channels co*8..+8, k = eg*8+j
        const int src = (lane & 56) | (lane >> 3);
        float o[8] = {};
#pragma unroll
        for (int j = 0; j < 8; j++) {
            float        hk = __shfl(h[j], src);
            const float* wr = &w2s[(eg * 8 + j) * 64 + co * 8];
            float4 wa = *(const float4*)wr;
            float4 wb = *(const float4*)(wr + 4);
            o[0] += hk * wa.x; o[1] += hk * wa.y; o[2] += hk * wa.z; o[3] += hk * wa.w;
            o[4] += hk * wb.x; o[5] += hk * wb.y; o[6] += hk * wb.z; o[7] += hk * wb.w;
        }
#pragma unroll
        for (int off = 8; off <= 32; off <<= 1)
#pragma unroll
            for (int i = 0; i < 8; i++) o[i] += __shfl_xor(o[i], off);

        if (eg == 0) {
            uint4 ob;
            ob.x = (unsigned int)f2bf(o[0]) | ((unsigned int)f2bf(o[1]) << 16);
            ob.y = (unsigned int)f2bf(o[2]) | ((unsigned int)f2bf(o[3]) << 16);
            ob.z = (unsigned int)f2bf(o[4]) | ((unsigned int)f2bf(o[5]) << 16);
            ob.w = (unsigned int)f2bf(o[6]) | ((unsigned int)f2bf(o[7]) << 16);
            *(uint4*)&hw[(size_t)row * 64 + co * 8] = ob;
        }
    }
}

// ---------------- layer 2: pull-agg + bias + log_softmax -> fp32 out ----------------

__global__ __launch_bounds__(256) void agg_l2(const unsigned short* __restrict__ B,
                                              const int* __restrict__ csr,
                                              const int* __restrict__ ptr,
                                              const float* __restrict__ dis,
                                              const float* __restrict__ b2,
                                              float* __restrict__ out, int N) {
    const int row  = blockIdx.x * 4 + (threadIdx.x >> 6);
    const int lane = threadIdx.x & 63;
    if (row >= N) return;
    const int eg = lane >> 3;
    const int co = lane & 7;

    const int   s0 = ptr[row];
    const int   s1 = ptr[row + 1];
    const float di = dis[row];

    float acc[8] = {};
    gather8(B, csr, dis, s0, s1, lane, eg, co, acc);

    uint4 us = *(const uint4*)&B[(size_t)row * 64 + co * 8];
    float bs[8];
    bf8_unpack(us, bs);
    float bb[8];
    *(float4*)&bb[0] = *(const float4*)&b2[co * 8];
    *(float4*)&bb[4] = *(const float4*)&b2[co * 8 + 4];

    float v[8];
#pragma unroll
    for (int i = 0; i < 8; i++) v[i] = (acc[i] + bs[i] * di) * di + bb[i];

    float m = v[0];
#pragma unroll
    for (int i = 1; i < 8; i++) m = fmaxf(m, v[i]);
#pragma unroll
    for (int off = 1; off <= 4; off <<= 1) m = fmaxf(m, __shfl_xor(m, off));
    float s = 0.f;
#pragma unroll
    for (int i = 0; i < 8; i++) s += __expf(v[i] - m);
#pragma unroll
    for (int off = 1; off <= 4; off <<= 1) s += __shfl_xor(s, off);
    float lse = m + __logf(s);

    if (eg == 0) {
        float4 oa = make_float4(v[0] - lse, v[1] - lse, v[2] - lse, v[3] - lse);
        float4 ob = make_float4(v[4] - lse, v[5] - lse, v[6] - lse, v[7] - lse);
        *(float4*)&out[(size_t)row * 64 + co * 8]     = oa;
        *(float4*)&out[(size_t)row * 64 + co * 8 + 4] = ob;
    }
}

// ---------------- launch ----------------

extern "C" void kernel_launch(void* const* d_in, const int* in_sizes, int n_in,
                              void* d_out, int out_size, void* d_ws, size_t ws_size,
                              hipStream_t stream) {
    const float* x   = (const float*)d_in[0];
    const int*   ei  = (const int*)d_in[1];
    const float* W1  = (const float*)d_in[2];
    const float* b1  = (const float*)d_in[3];
    const float* W2  = (const float*)d_in[4];
    const float* b2  = (const float*)d_in[5];
    float*       out = (float*)d_out;

    const int  N   = in_sizes[0] / 128;
    const int  E   = in_sizes[1] / 2;
    const int* src = ei;
    const int* dst = ei + E;
    const int  NB  = (N + 1023) / 1024;

    int shift = 9;
    while (((N - 1) >> shift) >= 256) shift++;
    const int NBUCK = ((N - 1) >> shift) + 1;
    const int CAP   = ((E / NBUCK) * 3 / 2 + 255) & ~255;

    auto align256 = [](size_t v) { return (v + 255) & ~(size_t)255; };
    char*           p        = (char*)d_ws;
    float*          dis      = (float*)p;          p += align256((size_t)N * 4);
    int*            ptr      = (int*)p;            p += align256((size_t)(N + 1) * 4);
    int*            hist     = (int*)p;            p += align256((size_t)N * 4);
    int*            partials = (int*)p;            p += align256((size_t)NB * 4);
    int*            bcur     = (int*)p;            p += align256(256 * 4);
    int*            csr      = (int*)p;            p += align256((size_t)E * 4);
    int2*           bbuf     = (int2*)p;           p += align256((size_t)NBUCK * CAP * 8);
    unsigned short* xwb      = (unsigned short*)p; p += align256((size_t)N * 64 * 2);
    unsigned short* hwb      = (unsigned short*)p; p += align256((size_t)N * 64 * 2);

    bcur_init<<<1, 256, 0, stream>>>(bcur, NBUCK, CAP);
    passA<<<(E + PASSA_EDGES - 1) / PASSA_EDGES, 256, 0, stream>>>(src, dst, bcur, bbuf, E, CAP, shift);
    hist_dis<<<NBUCK, 256, 0, stream>>>(bbuf, bcur, hist, dis, N, CAP, shift);
    scan_partial<<<NB, 256, 0, stream>>>(hist, partials, N);
    scan_offsets<<<1, 256, 0, stream>>>(partials, NB);
    scan_apply<<<NB, 256, 0, stream>>>(hist, partials, ptr, N);
    passB<<<NBUCK, 256, 0, stream>>>(bbuf, bcur, ptr, csr, N, CAP, shift);

    gemm64_bf16<128><<<(N + 63) / 64, 256, 0, stream>>>(x, W1, xwb, N);
    agg_l1<<<(N + 15) / 16, 256, 0, stream>>>(xwb, csr, ptr, dis, b1, W2, hwb, N);
    agg_l2<<<(N + 3) / 4, 256, 0, stream>>>(hwb, csr, ptr, dis, b2, out, N);
}

// Round 11
// 317.031 us; speedup vs baseline: 1.0318x; 1.0318x over previous
//
#include <hip/hip_runtime.h>
#include <cstdint>
#include <cstddef>

#define PASSA_EDGES 8192
#define PASSB_CAP   12288   // LDS csr-image capacity (ints); max bucket ~8700 for this input

// ---------------- bf16 helpers ----------------

__device__ __forceinline__ unsigned short f2bf(float f) {  // RNE
    unsigned int u = __float_as_uint(f);
    u += 0x7FFFu + ((u >> 16) & 1u);
    return (unsigned short)(u >> 16);
}

// fma 8 bf16 (packed in uint4) * w into acc[8]
__device__ __forceinline__ void bf8_fma(uint4 u, float w, float* acc) {
    acc[0] += __uint_as_float(u.x << 16) * w;
    acc[1] += __uint_as_float(u.x & 0xFFFF0000u) * w;
    acc[2] += __uint_as_float(u.y << 16) * w;
    acc[3] += __uint_as_float(u.y & 0xFFFF0000u) * w;
    acc[4] += __uint_as_float(u.z << 16) * w;
    acc[5] += __uint_as_float(u.z & 0xFFFF0000u) * w;
    acc[6] += __uint_as_float(u.w << 16) * w;
    acc[7] += __uint_as_float(u.w & 0xFFFF0000u) * w;
}
__device__ __forceinline__ void bf8_unpack(uint4 u, float* v) {
    v[0] = __uint_as_float(u.x << 16);
    v[1] = __uint_as_float(u.x & 0xFFFF0000u);
    v[2] = __uint_as_float(u.y << 16);
    v[3] = __uint_as_float(u.y & 0xFFFF0000u);
    v[4] = __uint_as_float(u.z << 16);
    v[5] = __uint_as_float(u.z & 0xFFFF0000u);
    v[6] = __uint_as_float(u.w << 16);
    v[7] = __uint_as_float(u.w & 0xFFFF0000u);
}

// ---------------- bucket cursor init ----------------

__global__ void bcur_init(int* __restrict__ bcur, int NBUCK, int CAP) {
    int b = threadIdx.x;
    if (b < NBUCK) bcur[b] = b * CAP;
}

// ---------------- pass A: bin (src,dst) by coarse dst bucket into slabs ----------------

__global__ __launch_bounds__(256) void passA(const int* __restrict__ src,
                                             const int* __restrict__ dst,
                                             int* __restrict__ bcur,
                                             int2* __restrict__ bbuf, int E,
                                             int CAP, int shift) {
    __shared__ int2 bins[PASSA_EDGES];
    __shared__ int  cnt[256], off[256], cur[256], gbase[256];
    const int t  = threadIdx.x;
    const int e0 = blockIdx.x * PASSA_EDGES;
    const int n  = min(PASSA_EDGES, E - e0);

    cnt[t] = 0;
    __syncthreads();
    for (int i = t; i < n; i += 256) atomicAdd(&cnt[dst[e0 + i] >> shift], 1);
    __syncthreads();

    int v = cnt[t];
    off[t] = v;
    __syncthreads();
    for (int o = 1; o < 256; o <<= 1) {
        int u = (t >= o) ? off[t - o] : 0;
        __syncthreads();
        off[t] += u;
        __syncthreads();
    }
    int excl = off[t] - v;
    off[t]   = excl;
    cur[t]   = excl;
    __syncthreads();

    for (int i = t; i < n; i += 256) {
        int d = dst[e0 + i];
        int s = src[e0 + i];
        int p = atomicAdd(&cur[d >> shift], 1);
        bins[p] = make_int2(s, d);
    }
    if (cnt[t] > 0) gbase[t] = atomicAdd(&bcur[t], cnt[t]);
    __syncthreads();

    const int w = t >> 6, lane = t & 63;
    for (int b = w; b < 256; b += 4) {
        int c = cnt[b];
        if (c == 0) continue;
        int lo  = off[b], go = gbase[b];
        int lim = (b + 1) * CAP;
        if (go + c > lim) c = max(0, lim - go);
        for (int i = lane; i < c; i += 64) bbuf[go + i] = bins[lo + i];
    }
}

// ---------------- per-bucket histogram + dis ----------------

__global__ __launch_bounds__(256) void hist_dis(const int2* __restrict__ bbuf,
                                                const int* __restrict__ bcur,
                                                int* __restrict__ hist,
                                                float* __restrict__ dis,
                                                int N, int CAP, int shift) {
    __shared__ int cnt[1024];
    const int b     = blockIdx.x;
    const int node0 = b << shift;
    const int nn    = min(1 << shift, N - node0);
    for (int j = threadIdx.x; j < nn; j += 256) cnt[j] = 0;
    __syncthreads();
    const int start = b * CAP, end = bcur[b];
    for (int e = start + threadIdx.x; e < end; e += 256)
        atomicAdd(&cnt[bbuf[e].y - node0], 1);
    __syncthreads();
    for (int j = threadIdx.x; j < nn; j += 256) {
        int c = cnt[j];
        hist[node0 + j] = c;
        dis[node0 + j]  = rsqrtf((float)(c + 1));  // +1 self loop
    }
}

// ---------------- 3-phase exclusive scan hist[0..N) -> ptr[0..N] ----------------

__global__ __launch_bounds__(256) void scan_partial(const int* __restrict__ hist,
                                                    int* __restrict__ partials, int N) {
    __shared__ int red[256];
    const int t    = threadIdx.x;
    const int base = blockIdx.x * 1024 + t * 4;
    int s = 0;
    if (base + 3 < N) {
        int4 v = *(const int4*)&hist[base];
        s = v.x + v.y + v.z + v.w;
    } else {
        for (int i = 0; i < 4; i++)
            if (base + i < N) s += hist[base + i];
    }
    red[t] = s;
    __syncthreads();
    for (int off = 128; off; off >>= 1) {
        if (t < off) red[t] += red[t + off];
        __syncthreads();
    }
    if (t == 0) partials[blockIdx.x] = red[0];
}

__global__ __launch_bounds__(256) void scan_offsets(int* __restrict__ partials, int NB) {
    __shared__ int tmp[256];
    const int t = threadIdx.x;
    int v = (t < NB) ? partials[t] : 0;
    tmp[t] = v;
    __syncthreads();
    for (int off = 1; off < 256; off <<= 1) {
        int u = (t >= off) ? tmp[t - off] : 0;
        __syncthreads();
        tmp[t] += u;
        __syncthreads();
    }
    if (t < NB) partials[t] = tmp[t] - v;
}

__global__ __launch_bounds__(256) void scan_apply(const int* __restrict__ hist,
                                                  const int* __restrict__ partials,
                                                  int* __restrict__ ptr, int N) {
    __shared__ int tsum[256];
    const int t    = threadIdx.x;
    const int base = blockIdx.x * 1024 + t * 4;
    int v[4];
    int s = 0;
    for (int i = 0; i < 4; i++) {
        v[i] = (base + i < N) ? hist[base + i] : 0;
        s += v[i];
    }
    tsum[t] = s;
    __syncthreads();
    for (int off = 1; off < 256; off <<= 1) {
        int u = (t >= off) ? tsum[t - off] : 0;
        __syncthreads();
        tsum[t] += u;
        __syncthreads();
    }
    int run = partials[blockIdx.x] + tsum[t] - s;
    for (int i = 0; i < 4; i++) {
        if (base + i < N) {
            ptr[base + i] = run;
            run += v[i];
        }
    }
    if (base <= N - 1 && N - 1 < base + 4) ptr[N] = run;  // total = E
}

// ---------------- pass B: per-bucket LDS scatter -> contiguous csr write ----------------

__global__ __launch_bounds__(256) void passB(const int2* __restrict__ bbuf,
                                             const int* __restrict__ bcur,
                                             const int* __restrict__ ptr,
                                             int* __restrict__ csr,
                                             int N, int CAP, int shift) {
    __shared__ int lcnt[1024];
    __shared__ int lcsr[PASSB_CAP];
    const int b     = blockIdx.x;
    const int node0 = b << shift;
    const int nn    = min(1 << shift, N - node0);
    const int cbase = ptr[node0];
    const int csize = ptr[node0 + nn] - cbase;

    for (int j = threadIdx.x; j < nn; j += 256) lcnt[j] = ptr[node0 + j] - cbase;
    __syncthreads();

    const int start = b * CAP, end = bcur[b];
    if (csize <= PASSB_CAP) {
        for (int e = start + threadIdx.x; e < end; e += 256) {
            int2 pr = bbuf[e];
            int  p  = atomicAdd(&lcnt[pr.y - node0], 1);
            lcsr[p] = pr.x;
        }
        __syncthreads();
        for (int i = threadIdx.x; i < csize; i += 256) csr[cbase + i] = lcsr[i];
    } else {  // fallback: direct global scatter
        for (int e = start + threadIdx.x; e < end; e += 256) {
            int2 pr = bbuf[e];
            int  p  = atomicAdd(&lcnt[pr.y - node0], 1);
            csr[cbase + p] = pr.x;
        }
    }
}

// ---------------- GEMM: Yb[N x 64](bf16) = X[N x K] @ W[K x 64] ----------------
// #pragma unroll 2 REQUIRED (full unroll -> 256 VGPR + scratch spill, R6).

template <int K>
__global__ __launch_bounds__(256) void gemm64_bf16(const float* __restrict__ X,
                                                   const float* __restrict__ W,
                                                   unsigned short* __restrict__ Yb, int N) {
    constexpr int LDX = K + 4;
    __shared__ float xs[64 * LDX];
    __shared__ float ws[K * 64];
    const int tid  = threadIdx.x;
    const int row0 = blockIdx.x * 64;

    const float4* W4 = (const float4*)W;
    for (int i = tid; i < K * 16; i += 256) ((float4*)ws)[i] = W4[i];

    const float4* X4  = (const float4*)(X + (size_t)row0 * K);
    const int     nf4 = (row0 < N ? min(64, N - row0) : 0) * (K / 4);
    for (int i = tid; i < 16 * K; i += 256) {
        float4 v = make_float4(0.f, 0.f, 0.f, 0.f);
        if (i < nf4) v = X4[i];
        int r  = i / (K / 4);
        int kk = (i % (K / 4)) * 4;
        *(float4*)&xs[r * LDX + kk] = v;
    }
    __syncthreads();

    const int cg = tid & 15;
    const int rg = tid >> 4;

    float acc[4][4] = {};
#pragma unroll 2
    for (int k = 0; k < K; k += 4) {
        float4 xf[4], wf[4];
#pragma unroll
        for (int i = 0; i < 4; i++) xf[i] = *(const float4*)&xs[(rg * 4 + i) * LDX + k];
#pragma unroll
        for (int j = 0; j < 4; j++) wf[j] = *(const float4*)&ws[(k + j) * 64 + cg * 4];
#pragma unroll
        for (int i = 0; i < 4; i++) {
            float4 xv = xf[i];
            acc[i][0] += xv.x * wf[0].x + xv.y * wf[1].x + xv.z * wf[2].x + xv.w * wf[3].x;
            acc[i][1] += xv.x * wf[0].y + xv.y * wf[1].y + xv.z * wf[2].y + xv.w * wf[3].y;
            acc[i][2] += xv.x * wf[0].z + xv.y * wf[1].z + xv.z * wf[2].z + xv.w * wf[3].z;
            acc[i][3] += xv.x * wf[0].w + xv.y * wf[1].w + xv.z * wf[2].w + xv.w * wf[3].w;
        }
    }

#pragma unroll
    for (int i = 0; i < 4; i++) {
        int r = row0 + rg * 4 + i;
        if (r < N) {
            ushort4 o;
            o.x = f2bf(acc[i][0]); o.y = f2bf(acc[i][1]);
            o.z = f2bf(acc[i][2]); o.w = f2bf(acc[i][3]);
            *(ushort4*)&Yb[(size_t)r * 64 + cg * 4] = o;
        }
    }
}

// ---------------- gather core: acc[8] += sum_e B[src_e]*dis[src_e] ----------------
// lane = eg*8+co. 8 edges/group, 4 independent groups in flight per iteration
// (gather is MLP-bound: ~200cyc L2 latency x ~9B/cyc/CU demand needs ~4
// outstanding loads/wave). Overrun slots carry w=0 (row-0 loads, harmless).
// After the xor-reduce EVERY lane holds the full acc for its channel octet.

__device__ __forceinline__ void gather8(const unsigned short* __restrict__ B,
                                        const int* __restrict__ csr,
                                        const float* __restrict__ dis,
                                        int s0, int s1, int lane, int eg, int co,
                                        float* acc) {
    for (int base = s0; base < s1; base += 64) {
        int   sv = 0;
        float wv = 0.0f;
        int   e  = base + lane;
        if (e < s1) {
            sv = csr[e];
            wv = dis[sv];
        }
        const int cnt = min(64, s1 - base);
        for (int gg = 0; gg < cnt; gg += 32) {
            int   sA = __shfl(sv, gg + eg);
            float wA = __shfl(wv, gg + eg);
            int   sB = __shfl(sv, gg + 8 + eg);
            float wB = __shfl(wv, gg + 8 + eg);
            int   sC = __shfl(sv, gg + 16 + eg);
            float wC = __shfl(wv, gg + 16 + eg);
            int   sD = __shfl(sv, gg + 24 + eg);
            float wD = __shfl(wv, gg + 24 + eg);
            uint4 uA = *(const uint4*)&B[(size_t)sA * 64 + co * 8];
            uint4 uB = *(const uint4*)&B[(size_t)sB * 64 + co * 8];
            uint4 uC = *(const uint4*)&B[(size_t)sC * 64 + co * 8];
            uint4 uD = *(const uint4*)&B[(size_t)sD * 64 + co * 8];
            bf8_fma(uA, wA, acc);
            bf8_fma(uB, wB, acc);
            bf8_fma(uC, wC, acc);
            bf8_fma(uD, wD, acc);
        }
    }
#pragma unroll
    for (int off = 8; off <= 32; off <<= 1)
#pragma unroll
        for (int i = 0; i < 8; i++) acc[i] += __shfl_xor(acc[i], off);
}

// ---------------- layer 1: pull-agg + relu + fused gemm2 -> bf16 hw ----------------
// gemm2 uses the R9 conflict-free mapping: lane=(eg2=lane>>4, cq=lane&15),
// k=eg2*16+j, W2 read at w2s[k*64+cq*4] (all 32 banks, 2-way = free). R10's
// co*8 float4 pairs hit 4-way conflicts on half the banks (6.4e6 SQ_LDS_BANK_CONFLICT).

__global__ __launch_bounds__(256) void agg_l1(const unsigned short* __restrict__ B,
                                              const int* __restrict__ csr,
                                              const int* __restrict__ ptr,
                                              const float* __restrict__ dis,
                                              const float* __restrict__ b1,
                                              const float* __restrict__ W2,
                                              unsigned short* __restrict__ hw, int N) {
    __shared__ float w2s[64 * 64];
    for (int i = threadIdx.x; i < 1024; i += 256)
        ((float4*)w2s)[i] = ((const float4*)W2)[i];
    __syncthreads();

    const int wid  = threadIdx.x >> 6;
    const int lane = threadIdx.x & 63;
    const int eg   = lane >> 3;
    const int co   = lane & 7;
    const int eg2  = lane >> 4;
    const int cq   = lane & 15;

    for (int g = 0; g < 4; g++) {
        const int row = blockIdx.x * 16 + g * 4 + wid;
        if (row >= N) continue;

        const int   s0 = ptr[row];
        const int   s1 = ptr[row + 1];
        const float di = dis[row];

        float acc[8] = {};
        gather8(B, csr, dis, s0, s1, lane, eg, co, acc);

        uint4 us = *(const uint4*)&B[(size_t)row * 64 + co * 8];
        float bs[8];
        bf8_unpack(us, bs);
        float bb[8];
        *(float4*)&bb[0] = *(const float4*)&b1[co * 8];
        *(float4*)&bb[4] = *(const float4*)&b1[co * 8 + 4];

        float h[8];
#pragma unroll
        for (int i = 0; i < 8; i++)
            h[i] = fmaxf((acc[i] + bs[i] * di) * di + bb[i], 0.f);

        // fused gemm2: lane (eg2,cq) -> out channels cq*4..+3, k = eg2*16+j.
        // source lane holds channel k in h[k&7]; any lane with (lane&7)==k>>3.
        float o[4] = {0.f, 0.f, 0.f, 0.f};
#pragma unroll
        for (int j = 0; j < 16; j++) {
            const int k    = eg2 * 16 + j;
            const int srcl = (lane & 56) | (eg2 * 2 + (j >> 3));
            float     hk   = __shfl(h[j & 7], srcl);
            const float4 wr = *(const float4*)&w2s[k * 64 + cq * 4];
            o[0] += hk * wr.x;
            o[1] += hk * wr.y;
            o[2] += hk * wr.z;
            o[3] += hk * wr.w;
        }
#pragma unroll
        for (int off = 16; off <= 32; off <<= 1)
#pragma unroll
            for (int i = 0; i < 4; i++) o[i] += __shfl_xor(o[i], off);

        if (eg2 == 0) {
            ushort4 ob;
            ob.x = f2bf(o[0]); ob.y = f2bf(o[1]);
            ob.z = f2bf(o[2]); ob.w = f2bf(o[3]);
            *(ushort4*)&hw[(size_t)row * 64 + cq * 4] = ob;
        }
    }
}

// ---------------- layer 2: pull-agg + bias + log_softmax -> fp32 out ----------------

__global__ __launch_bounds__(256) void agg_l2(const unsigned short* __restrict__ B,
                                              const int* __restrict__ csr,
                                              const int* __restrict__ ptr,
                                              const float* __restrict__ dis,
                                              const float* __restrict__ b2,
                                              float* __restrict__ out, int N) {
    const int row  = blockIdx.x * 4 + (threadIdx.x >> 6);
    const int lane = threadIdx.x & 63;
    if (row >= N) return;
    const int eg = lane >> 3;
    const int co = lane & 7;

    const int   s0 = ptr[row];
    const int   s1 = ptr[row + 1];
    const float di = dis[row];

    float acc[8] = {};
    gather8(B, csr, dis, s0, s1, lane, eg, co, acc);

    uint4 us = *(const uint4*)&B[(size_t)row * 64 + co * 8];
    float bs[8];
    bf8_unpack(us, bs);
    float bb[8];
    *(float4*)&bb[0] = *(const float4*)&b2[co * 8];
    *(float4*)&bb[4] = *(const float4*)&b2[co * 8 + 4];

    float v[8];
#pragma unroll
    for (int i = 0; i < 8; i++) v[i] = (acc[i] + bs[i] * di) * di + bb[i];

    float m = v[0];
#pragma unroll
    for (int i = 1; i < 8; i++) m = fmaxf(m, v[i]);
#pragma unroll
    for (int off = 1; off <= 4; off <<= 1) m = fmaxf(m, __shfl_xor(m, off));
    float s = 0.f;
#pragma unroll
    for (int i = 0; i < 8; i++) s += __expf(v[i] - m);
#pragma unroll
    for (int off = 1; off <= 4; off <<= 1) s += __shfl_xor(s, off);
    float lse = m + __logf(s);

    if (eg == 0) {
        float4 oa = make_float4(v[0] - lse, v[1] - lse, v[2] - lse, v[3] - lse);
        float4 ob = make_float4(v[4] - lse, v[5] - lse, v[6] - lse, v[7] - lse);
        *(float4*)&out[(size_t)row * 64 + co * 8]     = oa;
        *(float4*)&out[(size_t)row * 64 + co * 8 + 4] = ob;
    }
}

// ---------------- launch ----------------

extern "C" void kernel_launch(void* const* d_in, const int* in_sizes, int n_in,
                              void* d_out, int out_size, void* d_ws, size_t ws_size,
                              hipStream_t stream) {
    const float* x   = (const float*)d_in[0];
    const int*   ei  = (const int*)d_in[1];
    const float* W1  = (const float*)d_in[2];
    const float* b1  = (const float*)d_in[3];
    const float* W2  = (const float*)d_in[4];
    const float* b2  = (const float*)d_in[5];
    float*       out = (float*)d_out;

    const int  N   = in_sizes[0] / 128;
    const int  E   = in_sizes[1] / 2;
    const int* src = ei;
    const int* dst = ei + E;
    const int  NB  = (N + 1023) / 1024;

    int shift = 9;
    while (((N - 1) >> shift) >= 256) shift++;
    const int NBUCK = ((N - 1) >> shift) + 1;
    const int CAP   = ((E / NBUCK) * 3 / 2 + 255) & ~255;

    auto align256 = [](size_t v) { return (v + 255) & ~(size_t)255; };
    char*           p        = (char*)d_ws;
    float*          dis      = (float*)p;          p += align256((size_t)N * 4);
    int*            ptr      = (int*)p;            p += align256((size_t)(N + 1) * 4);
    int*            hist     = (int*)p;            p += align256((size_t)N * 4);
    int*            partials = (int*)p;            p += align256((size_t)NB * 4);
    int*            bcur     = (int*)p;            p += align256(256 * 4);
    int*            csr      = (int*)p;            p += align256((size_t)E * 4);
    int2*           bbuf     = (int2*)p;           p += align256((size_t)NBUCK * CAP * 8);
    unsigned short* xwb      = (unsigned short*)p; p += align256((size_t)N * 64 * 2);
    unsigned short* hwb      = (unsigned short*)p; p += align256((size_t)N * 64 * 2);

    bcur_init<<<1, 256, 0, stream>>>(bcur, NBUCK, CAP);
    passA<<<(E + PASSA_EDGES - 1) / PASSA_EDGES, 256, 0, stream>>>(src, dst, bcur, bbuf, E, CAP, shift);
    hist_dis<<<NBUCK, 256, 0, stream>>>(bbuf, bcur, hist, dis, N, CAP, shift);
    scan_partial<<<NB, 256, 0, stream>>>(hist, partials, N);
    scan_offsets<<<1, 256, 0, stream>>>(partials, NB);
    scan_apply<<<NB, 256, 0, stream>>>(hist, partials, ptr, N);
    passB<<<NBUCK, 256, 0, stream>>>(bbuf, bcur, ptr, csr, N, CAP, shift);

    gemm64_bf16<128><<<(N + 63) / 64, 256, 0, stream>>>(x, W1, xwb, N);
    agg_l1<<<(N + 15) / 16, 256, 0, stream>>>(xwb, csr, ptr, dis, b1, W2, hwb, N);
    agg_l2<<<(N + 3) / 4, 256, 0, stream>>>(hwb, csr, ptr, dis, b2, out, N);
}